// Round 7
// baseline (443.611 us; speedup 1.0000x reference)
//
#include <hip/hip_runtime.h>

#define BATCH 4096
#define NE 100000
#define ROWDW 68        // W1^T row stride in dwords (64 + 4 pad)

typedef __attribute__((ext_vector_type(8))) short bf16x8;
typedef __attribute__((ext_vector_type(4))) float f32x4;

union U4 { uint4 u4; bf16x8 v; };

struct GPtrs {
    const int* h0[5]; const int* h1[5];
    const int* r0[5]; const int* r1[5];
    const int* t0[5]; const int* t1[5];
};

// bf16 truncation pack: word = { hi16(lo) , hi16(hi)<<16 }  (lo -> low half)
__device__ __forceinline__ unsigned trunc2(float lo, float hi){
    return __builtin_amdgcn_perm(__float_as_uint(hi), __float_as_uint(lo), 0x07060302u);
}
__device__ __forceinline__ float bflo(unsigned u){ return __uint_as_float(u << 16); }
__device__ __forceinline__ float bfhi(unsigned u){ return __uint_as_float(u & 0xFFFF0000u); }
__device__ __forceinline__ float bf2f(unsigned short h){ return __uint_as_float(((unsigned)h) << 16); }
__device__ __forceinline__ unsigned addw(unsigned x, unsigned y){
    return trunc2(bflo(x)+bflo(y), bfhi(x)+bfhi(y));
}
__device__ __forceinline__ unsigned mulw(unsigned x, unsigned y){
    return trunc2(bflo(x)*bflo(y), bfhi(x)*bfhi(y));
}
__device__ __forceinline__ float sigm(float x){ return __builtin_amdgcn_rcpf(1.0f + __expf(-x)); }

// ---- prep: E (25.6MB f32) -> ebf (12.8MB bf16); R -> rbf ----
__global__ __launch_bounds__(256)
void prep_kernel(const float* __restrict__ E, const float* __restrict__ R,
                 unsigned short* __restrict__ ebf, unsigned short* __restrict__ rbf)
{
    const int EC = (NE*64)/8;      // 800000 chunks of 8
    const int RC = (100*64)/8;     // 800
    int stride = gridDim.x * blockDim.x;
    for (int c = blockIdx.x*blockDim.x + threadIdx.x; c < EC + RC; c += stride) {
        const float* src; unsigned short* dst;
        if (c < EC) { src = E + c*8;      dst = ebf + c*8; }
        else        { src = R + (c-EC)*8; dst = rbf + (c-EC)*8; }
        float4 a = *(const float4*)src;
        float4 b = *(const float4*)(src + 4);
        uint4 o;
        o.x = trunc2(a.x,a.y); o.y = trunc2(a.z,a.w);
        o.z = trunc2(b.x,b.y); o.w = trunc2(b.z,b.w);
        *(uint4*)dst = o;
    }
}

// grid = (BATCH/16, 5). block = 1024 = 16 waves. Each WAVE owns one (g,b).
// 16 waves/block: one resident block = 16 waves/CU (vs r6's 2x4); W1 staging
// amortized over 16 units. Zero barriers in hot path. (1024,4): cap 512 regs,
// no forced spilling (r3/r5 failure mode was forced 64-reg caps).
__global__ __launch_bounds__(1024, 4)
void group_kernel(GPtrs gp, const int* __restrict__ items,
                  const float* __restrict__ E,
                  const unsigned short* __restrict__ ebf,
                  const unsigned short* __restrict__ rbf,
                  const float* __restrict__ W1, const float* __restrict__ W2,
                  float* __restrict__ ws)
{
    const int g    = blockIdx.y;
    const int tid  = threadIdx.x;
    const int lane = tid & 63;
    const int wv   = tid >> 6;          // 0..15

    __shared__ unsigned w1t[64 * ROWDW];   // W1^T rows (j, k-pairs), bf16: 17408 B

    // ---- stage W1^T as bf16, once per block (16 waves cooperate) ----
    {
        int j  = tid & 63;
        int kb = tid >> 6;               // 0..15
        #pragma unroll
        for (int it = 0; it < 4; ++it) {
            int kp = kb + it*16;                   // k-pair 0..63
            float a = W1[(2*kp    )*64 + j];
            float b = W1[(2*kp + 1)*64 + j];
            w1t[j*ROWDW + kp] = trunc2(a, b);
        }
    }
    __syncthreads();    // only barrier in the kernel

    const int b = blockIdx.x*16 + wv;

    const int tcol = lane & 15;          // t within t-block (MFMA C col)
    const int q    = lane >> 4;          // k-quarter 0..3
    const int q4   = q * 4;              // k-pair base within A frag row

    // ---- indices for this (g,b), one per lane ----
    int vh0 = gp.h0[g][b*64 + lane];
    int vh1 = gp.h1[g][b*64 + lane];
    int vr0 = gp.r0[g][b*64 + lane];
    int vr1 = gp.r1[g][b*64 + lane];
    int vt0 = gp.t0[g][b*64 + lane];
    int vt1 = gp.t1[g][b*64 + lane];

    // ---- init embedding (mean of E[h0] rows; ddp (g==1): exact f32 E[items]) ----
    {
        float o0 = 0.f, o1 = 0.f, o2 = 0.f, o3 = 0.f;
        if (g == 1) {
            o0 = E[items[b]*64 + lane];
        } else {
            #pragma unroll
            for (int t = 0; t < 64; t += 4) {
                int r0_ = __shfl(vh0, t,   64);
                int r1_ = __shfl(vh0, t+1, 64);
                int r2_ = __shfl(vh0, t+2, 64);
                int r3_ = __shfl(vh0, t+3, 64);
                o0 += bf2f(ebf[r0_*64 + lane]); o1 += bf2f(ebf[r1_*64 + lane]);
                o2 += bf2f(ebf[r2_*64 + lane]); o3 += bf2f(ebf[r3_*64 + lane]);
            }
            o0 = ((o0+o1)+(o2+o3)) * (1.0f/64.0f);
        }
        ws[((g*3 + 0)*BATCH + b)*64 + lane] = o0;
    }

    #pragma unroll 1
    for (int L = 0; L < 2; ++L) {
        float part[4];

        #pragma unroll 1
        for (int tb = 0; tb < 4; ++tb) {
            const int t_ = tb*16 + tcol;
            int hr0 = __shfl(vh0, t_, 64);
            int pr0 = __shfl(vr0, t_, 64);
            // ---- B-frags: direct bf16 row loads (uint4 = 8 bf16 = one k-slice) ----
            const uint4* hp = (const uint4*)(ebf + hr0*64);
            const uint4* pp = (const uint4*)(rbf + pr0*64);
            U4 f0, f1, f2, f3;
            f0.u4 = hp[q];            // h, k 0..31 slice q
            f1.u4 = hp[4 + q];        // h, k 32..63
            f2.u4 = pp[q];            // p, k 0..31
            f3.u4 = pp[4 + q];        // p, k 32..63
            if (L == 1) {
                int hr1 = __shfl(vh1, t_, 64);
                int pr1 = __shfl(vr1, t_, 64);
                const uint4* hq = (const uint4*)(ebf + hr1*64);
                const uint4* pq = (const uint4*)(rbf + pr1*64);
                uint4 x0 = hq[q], x1 = hq[4+q], y0 = pq[q], y1 = pq[4+q];
                f0.u4 = make_uint4(addw(f0.u4.x,x0.x), addw(f0.u4.y,x0.y),
                                   addw(f0.u4.z,x0.z), addw(f0.u4.w,x0.w));
                f1.u4 = make_uint4(addw(f1.u4.x,x1.x), addw(f1.u4.y,x1.y),
                                   addw(f1.u4.z,x1.z), addw(f1.u4.w,x1.w));
                f2.u4 = make_uint4(mulw(f2.u4.x,y0.x), mulw(f2.u4.y,y0.y),
                                   mulw(f2.u4.z,y0.z), mulw(f2.u4.w,y0.w));
                f3.u4 = make_uint4(mulw(f3.u4.x,y1.x), mulw(f3.u4.y,y1.y),
                                   mulw(f3.u4.z,y1.z), mulw(f3.u4.w,y1.w));
            }

            // ---- C^T[j][t] via MFMA; fold sigmoid & W2 ----
            float pt = 0.f;
            #pragma unroll
            for (int jt = 0; jt < 4; ++jt) {
                const unsigned* wb = &w1t[(jt*16 + tcol)*ROWDW + q4];
                U4 wf0, wf1, wf2, wf3;
                wf0.u4 = *(const uint4*)(wb);
                wf1.u4 = *(const uint4*)(wb + 16);
                wf2.u4 = *(const uint4*)(wb + 32);
                wf3.u4 = *(const uint4*)(wb + 48);
                f32x4 acc = {0.f, 0.f, 0.f, 0.f};
                acc = __builtin_amdgcn_mfma_f32_16x16x32_bf16(wf0.v, f0.v, acc, 0,0,0);
                acc = __builtin_amdgcn_mfma_f32_16x16x32_bf16(wf1.v, f1.v, acc, 0,0,0);
                acc = __builtin_amdgcn_mfma_f32_16x16x32_bf16(wf2.v, f2.v, acc, 0,0,0);
                acc = __builtin_amdgcn_mfma_f32_16x16x32_bf16(wf3.v, f3.v, acc, 0,0,0);
                float4 w2v = *(const float4*)(W2 + jt*16 + q4);
                pt += sigm(acc[0])*w2v.x + sigm(acc[1])*w2v.y
                    + sigm(acc[2])*w2v.z + sigm(acc[3])*w2v.w;
            }
            part[tb] = pt;
        }

        // ---- logits (quarter-replicated) + in-wave softmax, no max-sub ----
        float att[4]; float den = 0.f;
        #pragma unroll
        for (int tb = 0; tb < 4; ++tb) {
            float p = part[tb];
            p += __shfl_xor(p, 16, 64);
            p += __shfl_xor(p, 32, 64);
            float e = __expf(sigm(p));          // logits in (0,1): exp safe
            att[tb] = e;
            e += __shfl_xor(e, 1, 64);
            e += __shfl_xor(e, 2, 64);
            e += __shfl_xor(e, 4, 64);
            e += __shfl_xor(e, 8, 64);
            den += e;
        }
        float rden = __builtin_amdgcn_rcpf(den);
        #pragma unroll
        for (int tb = 0; tb < 4; ++tb) att[tb] *= rden;

        // ---- PV: out[d] = sum_t att_t * ebf[tIdx[t]][d], d = lane ----
        int vt = (L == 0) ? vt0 : vt1;
        float o0 = 0.f, o1 = 0.f, o2 = 0.f, o3 = 0.f;
        #pragma unroll
        for (int tb = 0; tb < 4; ++tb) {
            #pragma unroll
            for (int u = 0; u < 16; u += 4) {
                int t = tb*16 + u;
                int r0_ = __shfl(vt, t,   64);
                int r1_ = __shfl(vt, t+1, 64);
                int r2_ = __shfl(vt, t+2, 64);
                int r3_ = __shfl(vt, t+3, 64);
                float a0_ = __shfl(att[tb], u,   64);
                float a1_ = __shfl(att[tb], u+1, 64);
                float a2_ = __shfl(att[tb], u+2, 64);
                float a3_ = __shfl(att[tb], u+3, 64);
                o0 = fmaf(a0_, bf2f(ebf[r0_*64 + lane]), o0);
                o1 = fmaf(a1_, bf2f(ebf[r1_*64 + lane]), o1);
                o2 = fmaf(a2_, bf2f(ebf[r2_*64 + lane]), o2);
                o3 = fmaf(a3_, bf2f(ebf[r3_*64 + lane]), o3);
            }
        }
        ws[((g*3 + 1 + L)*BATCH + b)*64 + lane] = (o0+o1)+(o2+o3);
    }
}

// score[b] = sigmoid( sum_i (kg[i]+kgp[i])·ddi1[i] + 2·ddi[i]·ddo1[i] )
__launch_bounds__(256, 4)
__global__ void combine_kernel(const float* __restrict__ ws, float* __restrict__ out)
{
    const int tid  = threadIdx.x;
    const int lane = tid & 63;
    const int wv   = tid >> 6;
    const int b    = blockIdx.x*4 + wv;
    float acc = 0.f;
    #pragma unroll
    for (int i = 0; i < 3; ++i) {
        float kg   = ws[((0*3+i)*BATCH + b)*64 + lane];
        float ddi  = ws[((1*3+i)*BATCH + b)*64 + lane];
        float kgp  = ws[((2*3+i)*BATCH + b)*64 + lane];
        float ddi1 = ws[((3*3+i)*BATCH + b)*64 + lane];
        float ddo1 = ws[((4*3+i)*BATCH + b)*64 + lane];
        acc += (kg + kgp)*ddi1 + 2.0f*ddi*ddo1;
    }
    #pragma unroll
    for (int m = 32; m > 0; m >>= 1) acc += __shfl_xor(acc, m, 64);
    if (lane == 0) out[b] = 1.0f/(1.0f + __expf(-acc));
}

extern "C" void kernel_launch(void* const* d_in, const int* in_sizes, int n_in,
                              void* d_out, int out_size, void* d_ws, size_t ws_size,
                              hipStream_t stream)
{
    // input order: 0 items; then 8 prefixes x {h0,h1,r0,r1,t0,t1}:
    // kgi@1, ddp@7, kgp@13, ddo@19(dead), kgi1@25(dead), ddp1@31, kgp1@37(dead), ddo1@43;
    // 49 emb0(unused), 50 emb1(unused), 51 entity_emb, 52 relation_emb, 53 W1, 54 W2
    const int gbase[5] = {1, 7, 13, 31, 43};   // kgi, ddp, kgp, ddp1, ddo1
    GPtrs gp;
    for (int g = 0; g < 5; ++g) {
        gp.h0[g] = (const int*)d_in[gbase[g]+0];
        gp.h1[g] = (const int*)d_in[gbase[g]+1];
        gp.r0[g] = (const int*)d_in[gbase[g]+2];
        gp.r1[g] = (const int*)d_in[gbase[g]+3];
        gp.t0[g] = (const int*)d_in[gbase[g]+4];
        gp.t1[g] = (const int*)d_in[gbase[g]+5];
    }
    const int*   items = (const int*)d_in[0];
    const float* E     = (const float*)d_in[51];
    const float* R     = (const float*)d_in[52];
    const float* W1    = (const float*)d_in[53];
    const float* W2    = (const float*)d_in[54];

    // d_ws layout: [0, 15728640) f32 outputs (5 groups x 3 embs x [B,64]);
    //              [15728640, +12.8MB) ebf; then rbf (12.8KB). Total ~28.6 MB.
    float*          ws  = (float*)d_ws;
    unsigned short* ebf = (unsigned short*)((char*)d_ws + 15728640);
    unsigned short* rbf = (unsigned short*)((char*)d_ws + 15728640 + 12800000);

    prep_kernel<<<1024, 256, 0, stream>>>(E, R, ebf, rbf);
    dim3 grid(BATCH/16, 5);
    group_kernel<<<grid, 1024, 0, stream>>>(gp, items, E, ebf, rbf, W1, W2, ws);
    combine_kernel<<<BATCH/4, 256, 0, stream>>>(ws, (float*)d_out);
}

// Round 8
// 183.751 us; speedup vs baseline: 2.4142x; 2.4142x over previous
//
#include <hip/hip_runtime.h>

#define BATCH 4096
#define NE 100000
#define ROWDW 68        // W1^T row stride in dwords (64 + 4 pad)

typedef __attribute__((ext_vector_type(8))) short bf16x8;
typedef __attribute__((ext_vector_type(4))) float f32x4;

union U4 { uint4 u4; bf16x8 v; };

struct GPtrs {
    const int* h0[5]; const int* h1[5];
    const int* r0[5]; const int* r1[5];
    const int* t0[5]; const int* t1[5];
};

// bf16 truncation pack: word = { hi16(lo) , hi16(hi)<<16 }  (lo -> low half)
__device__ __forceinline__ unsigned trunc2(float lo, float hi){
    return __builtin_amdgcn_perm(__float_as_uint(hi), __float_as_uint(lo), 0x07060302u);
}
__device__ __forceinline__ float bflo(unsigned u){ return __uint_as_float(u << 16); }
__device__ __forceinline__ float bfhi(unsigned u){ return __uint_as_float(u & 0xFFFF0000u); }
__device__ __forceinline__ float bf2f(unsigned short h){ return __uint_as_float(((unsigned)h) << 16); }
__device__ __forceinline__ unsigned addw(unsigned x, unsigned y){
    return trunc2(bflo(x)+bflo(y), bfhi(x)+bfhi(y));
}
__device__ __forceinline__ unsigned mulw(unsigned x, unsigned y){
    return trunc2(bflo(x)*bflo(y), bfhi(x)*bfhi(y));
}
__device__ __forceinline__ float sigm(float x){ return __builtin_amdgcn_rcpf(1.0f + __expf(-x)); }

// ---- prep: E (25.6MB f32) -> ebf (12.8MB bf16); R -> rbf ----
__global__ __launch_bounds__(256)
void prep_kernel(const float* __restrict__ E, const float* __restrict__ R,
                 unsigned short* __restrict__ ebf, unsigned short* __restrict__ rbf)
{
    const int EC = (NE*64)/8;      // 800000 chunks of 8
    const int RC = (100*64)/8;     // 800
    int stride = gridDim.x * blockDim.x;
    for (int c = blockIdx.x*blockDim.x + threadIdx.x; c < EC + RC; c += stride) {
        const float* src; unsigned short* dst;
        if (c < EC) { src = E + c*8;      dst = ebf + c*8; }
        else        { src = R + (c-EC)*8; dst = rbf + (c-EC)*8; }
        float4 a = *(const float4*)src;
        float4 b = *(const float4*)(src + 4);
        uint4 o;
        o.x = trunc2(a.x,a.y); o.y = trunc2(a.z,a.w);
        o.z = trunc2(b.x,b.y); o.w = trunc2(b.z,b.w);
        *(uint4*)dst = o;
    }
}

// grid = (BATCH, 5). block = 256 = 4 waves; the BLOCK owns one (g,b); wave wv
// owns t-block wv (16 triples). Short per-wave chains, ~16 persistent frag
// regs (h/p frags live across both layers). (256,2): spill-safe cap (any
// tighter bound spilled 0.5GB in r3/r5/r7).
__global__ __launch_bounds__(256, 2)
void group_kernel(GPtrs gp, const int* __restrict__ items,
                  const float* __restrict__ E,
                  const unsigned short* __restrict__ ebf,
                  const unsigned short* __restrict__ rbf,
                  const float* __restrict__ W1, const float* __restrict__ W2,
                  float* __restrict__ ws)
{
    const int g    = blockIdx.y;
    const int b    = blockIdx.x;
    const int tid  = threadIdx.x;
    const int lane = tid & 63;
    const int wv   = tid >> 6;          // 0..3 = t-block

    __shared__ unsigned w1t[64 * ROWDW];   // W1^T rows (j, k-pairs), bf16: 17408 B
    __shared__ float red_log[64];          // attention logits (t = index)
    __shared__ float red_pv[4][64];        // per-wave partials (init & PV)

    // ---- stage W1^T as bf16, once per block ----
    {
        int j  = tid & 63;
        int kb = tid >> 6;
        #pragma unroll
        for (int it = 0; it < 16; ++it) {
            int kp = kb + it*4;                    // k-pair 0..63
            float a = W1[(2*kp    )*64 + j];
            float bb = W1[(2*kp + 1)*64 + j];
            w1t[j*ROWDW + kp] = trunc2(a, bb);
        }
    }

    const int tcol = lane & 15;          // t within this wave's t-block
    const int q    = lane >> 4;          // k-quarter 0..3
    const int q4   = q * 4;              // k-pair base within frag row
    const int t_   = wv*16 + tcol;       // global triple index for frag gather

    // ---- indices for this (g,b), one per lane (full 64-vectors) ----
    int vh0 = gp.h0[g][b*64 + lane];
    int vh1 = gp.h1[g][b*64 + lane];
    int vr0 = gp.r0[g][b*64 + lane];
    int vr1 = gp.r1[g][b*64 + lane];
    int vt0 = gp.t0[g][b*64 + lane];
    int vt1 = gp.t1[g][b*64 + lane];

    __syncthreads();   // w1t ready

    // ---- init embedding (4-wave parallel mean of E[h0]; ddp (g==1): f32 E[items]) ----
    if (g == 1) {
        if (wv == 0) ws[((g*3 + 0)*BATCH + b)*64 + lane] = E[items[b]*64 + lane];
    } else {
        float o0 = 0.f, o1 = 0.f, o2 = 0.f, o3 = 0.f;
        #pragma unroll
        for (int u = 0; u < 16; u += 4) {
            int t = wv*16 + u;
            int r0_ = __shfl(vh0, t,   64);
            int r1_ = __shfl(vh0, t+1, 64);
            int r2_ = __shfl(vh0, t+2, 64);
            int r3_ = __shfl(vh0, t+3, 64);
            o0 += bf2f(ebf[r0_*64 + lane]); o1 += bf2f(ebf[r1_*64 + lane]);
            o2 += bf2f(ebf[r2_*64 + lane]); o3 += bf2f(ebf[r3_*64 + lane]);
        }
        red_pv[wv][lane] = ((o0+o1)+(o2+o3));
        __syncthreads();
        if (wv == 0)
            ws[((g*3 + 0)*BATCH + b)*64 + lane] =
                (red_pv[0][lane]+red_pv[1][lane]+red_pv[2][lane]+red_pv[3][lane]) * (1.0f/64.0f);
    }

    // ---- layer-0 fragments for this wave's t-block (persist across layers) ----
    U4 f0, f1, f2, f3;
    {
        int hr0 = __shfl(vh0, t_, 64);
        int pr0 = __shfl(vr0, t_, 64);
        const uint4* hp = (const uint4*)(ebf + hr0*64);
        const uint4* pp = (const uint4*)(rbf + pr0*64);
        f0.u4 = hp[q];            // h, k 0..31 slice q
        f1.u4 = hp[4 + q];        // h, k 32..63
        f2.u4 = pp[q];            // p, k 0..31
        f3.u4 = pp[4 + q];        // p, k 32..63
    }

    #pragma unroll
    for (int L = 0; L < 2; ++L) {
        if (L == 1) {
            // in-place frag update: h += E[h1], p *= R[r1] (no h0/r0 re-gather)
            int hr1 = __shfl(vh1, t_, 64);
            int pr1 = __shfl(vr1, t_, 64);
            const uint4* hq = (const uint4*)(ebf + hr1*64);
            const uint4* pq = (const uint4*)(rbf + pr1*64);
            uint4 x0 = hq[q], x1 = hq[4+q], y0 = pq[q], y1 = pq[4+q];
            f0.u4 = make_uint4(addw(f0.u4.x,x0.x), addw(f0.u4.y,x0.y),
                               addw(f0.u4.z,x0.z), addw(f0.u4.w,x0.w));
            f1.u4 = make_uint4(addw(f1.u4.x,x1.x), addw(f1.u4.y,x1.y),
                               addw(f1.u4.z,x1.z), addw(f1.u4.w,x1.w));
            f2.u4 = make_uint4(mulw(f2.u4.x,y0.x), mulw(f2.u4.y,y0.y),
                               mulw(f2.u4.z,y0.z), mulw(f2.u4.w,y0.w));
            f3.u4 = make_uint4(mulw(f3.u4.x,y1.x), mulw(f3.u4.y,y1.y),
                               mulw(f3.u4.z,y1.z), mulw(f3.u4.w,y1.w));
        }

        // ---- C^T[j][t] via MFMA for this t-block; fold sigmoid & W2 ----
        float pt = 0.f;
        #pragma unroll
        for (int jt = 0; jt < 4; ++jt) {
            const unsigned* wb = &w1t[(jt*16 + tcol)*ROWDW + q4];
            U4 wf0, wf1, wf2, wf3;
            wf0.u4 = *(const uint4*)(wb);
            wf1.u4 = *(const uint4*)(wb + 16);
            wf2.u4 = *(const uint4*)(wb + 32);
            wf3.u4 = *(const uint4*)(wb + 48);
            f32x4 acc = {0.f, 0.f, 0.f, 0.f};
            acc = __builtin_amdgcn_mfma_f32_16x16x32_bf16(wf0.v, f0.v, acc, 0,0,0);
            acc = __builtin_amdgcn_mfma_f32_16x16x32_bf16(wf1.v, f1.v, acc, 0,0,0);
            acc = __builtin_amdgcn_mfma_f32_16x16x32_bf16(wf2.v, f2.v, acc, 0,0,0);
            acc = __builtin_amdgcn_mfma_f32_16x16x32_bf16(wf3.v, f3.v, acc, 0,0,0);
            float4 w2v = *(const float4*)(W2 + jt*16 + q4);
            pt += sigm(acc[0])*w2v.x + sigm(acc[1])*w2v.y
                + sigm(acc[2])*w2v.z + sigm(acc[3])*w2v.w;
        }
        // reduce across k-quarters -> full logit for t = wv*16 + tcol
        pt += __shfl_xor(pt, 16, 64);
        pt += __shfl_xor(pt, 32, 64);
        if (lane < 16) red_log[wv*16 + lane] = sigm(pt);
        __syncthreads();

        // ---- softmax over all 64 t (redundant per wave; t = lane) ----
        float e = __expf(red_log[lane]);      // logits in (0,1): exp safe
        float den = e;
        #pragma unroll
        for (int m = 32; m > 0; m >>= 1) den += __shfl_xor(den, m, 64);
        float att = e * __builtin_amdgcn_rcpf(den);

        // ---- PV: this wave sums its 16 target rows ----
        int vt = (L == 0) ? vt0 : vt1;
        float o0 = 0.f, o1 = 0.f, o2 = 0.f, o3 = 0.f;
        #pragma unroll
        for (int u = 0; u < 16; u += 4) {
            int t = wv*16 + u;
            int r0_ = __shfl(vt, t,   64);
            int r1_ = __shfl(vt, t+1, 64);
            int r2_ = __shfl(vt, t+2, 64);
            int r3_ = __shfl(vt, t+3, 64);
            float a0_ = __shfl(att, t,   64);
            float a1_ = __shfl(att, t+1, 64);
            float a2_ = __shfl(att, t+2, 64);
            float a3_ = __shfl(att, t+3, 64);
            o0 = fmaf(a0_, bf2f(ebf[r0_*64 + lane]), o0);
            o1 = fmaf(a1_, bf2f(ebf[r1_*64 + lane]), o1);
            o2 = fmaf(a2_, bf2f(ebf[r2_*64 + lane]), o2);
            o3 = fmaf(a3_, bf2f(ebf[r3_*64 + lane]), o3);
        }
        red_pv[wv][lane] = (o0+o1)+(o2+o3);
        __syncthreads();
        if (wv == 0)
            ws[((g*3 + 1 + L)*BATCH + b)*64 + lane] =
                red_pv[0][lane]+red_pv[1][lane]+red_pv[2][lane]+red_pv[3][lane];
    }
}

// score[b] = sigmoid( sum_i (kg[i]+kgp[i])·ddi1[i] + 2·ddi[i]·ddo1[i] )
__launch_bounds__(256, 4)
__global__ void combine_kernel(const float* __restrict__ ws, float* __restrict__ out)
{
    const int tid  = threadIdx.x;
    const int lane = tid & 63;
    const int wv   = tid >> 6;
    const int b    = blockIdx.x*4 + wv;
    float acc = 0.f;
    #pragma unroll
    for (int i = 0; i < 3; ++i) {
        float kg   = ws[((0*3+i)*BATCH + b)*64 + lane];
        float ddi  = ws[((1*3+i)*BATCH + b)*64 + lane];
        float kgp  = ws[((2*3+i)*BATCH + b)*64 + lane];
        float ddi1 = ws[((3*3+i)*BATCH + b)*64 + lane];
        float ddo1 = ws[((4*3+i)*BATCH + b)*64 + lane];
        acc += (kg + kgp)*ddi1 + 2.0f*ddi*ddo1;
    }
    #pragma unroll
    for (int m = 32; m > 0; m >>= 1) acc += __shfl_xor(acc, m, 64);
    if (lane == 0) out[b] = 1.0f/(1.0f + __expf(-acc));
}

extern "C" void kernel_launch(void* const* d_in, const int* in_sizes, int n_in,
                              void* d_out, int out_size, void* d_ws, size_t ws_size,
                              hipStream_t stream)
{
    // input order: 0 items; then 8 prefixes x {h0,h1,r0,r1,t0,t1}:
    // kgi@1, ddp@7, kgp@13, ddo@19(dead), kgi1@25(dead), ddp1@31, kgp1@37(dead), ddo1@43;
    // 49 emb0(unused), 50 emb1(unused), 51 entity_emb, 52 relation_emb, 53 W1, 54 W2
    const int gbase[5] = {1, 7, 13, 31, 43};   // kgi, ddp, kgp, ddp1, ddo1
    GPtrs gp;
    for (int g = 0; g < 5; ++g) {
        gp.h0[g] = (const int*)d_in[gbase[g]+0];
        gp.h1[g] = (const int*)d_in[gbase[g]+1];
        gp.r0[g] = (const int*)d_in[gbase[g]+2];
        gp.r1[g] = (const int*)d_in[gbase[g]+3];
        gp.t0[g] = (const int*)d_in[gbase[g]+4];
        gp.t1[g] = (const int*)d_in[gbase[g]+5];
    }
    const int*   items = (const int*)d_in[0];
    const float* E     = (const float*)d_in[51];
    const float* R     = (const float*)d_in[52];
    const float* W1    = (const float*)d_in[53];
    const float* W2    = (const float*)d_in[54];

    // d_ws layout: [0, 15728640) f32 outputs (5 groups x 3 embs x [B,64]);
    //              [15728640, +12.8MB) ebf; then rbf (12.8KB). Total ~28.6 MB.
    float*          ws  = (float*)d_ws;
    unsigned short* ebf = (unsigned short*)((char*)d_ws + 15728640);
    unsigned short* rbf = (unsigned short*)((char*)d_ws + 15728640 + 12800000);

    prep_kernel<<<1024, 256, 0, stream>>>(E, R, ebf, rbf);
    dim3 grid(BATCH, 5);
    group_kernel<<<grid, 256, 0, stream>>>(gp, items, E, ebf, rbf, W1, W2, ws);
    combine_kernel<<<BATCH/4, 256, 0, stream>>>(ws, (float*)d_out);
}